// Round 5
// baseline (498.521 us; speedup 1.0000x reference)
//
#include <hip/hip_runtime.h>
#include <math.h>

#define T_SZ 4096
#define B_SZ 16
#define CIN 256
#define N_H 8
#define D_H 32
#define M_C 16
#define TAU 5e-5f
#define RCAP (1<<19)

typedef unsigned char u8;
typedef unsigned int uint;
typedef unsigned short ushort;

using frag_ab = __attribute__((ext_vector_type(8))) short;   // 8 bf16 (4 VGPRs)
using frag_c  = __attribute__((ext_vector_type(4))) float;   // 4 fp32 acc

// ---- workspace layout (bytes) ----
#define O_FWT   0          // float[256*256] f_w^T [c][j] (for k_centers)
#define O_VWT   262144     // float[256*256]
#define O_WFH   524288     // bf16[256n][256k] hi/lo weight splits
#define O_WFL   655360
#define O_WVH   786432
#define O_WVL   917504
#define O_WPH   1048576
#define O_WPL   1179648
#define O_PX    1310720    // double[B*16*256]
#define O_C64   1835008    // double[128*16*32] normalized centers
#define O_C32   2359296    // float same
#define O_VC    2621440    // float value centers
#define O_COUT  2883584    // float centers_out
#define O_GPART 3145728    // float[128*8*528]
#define O_CNT   5308416    // int rescue counter
#define O_LIST  5308672    // uint[RCAP]
#define O_SELM  7405824    // u8[128*4096*2]
#define O_SELW  8454400    // float2[128*4096]
#define O_XS    12648704   // bf16 xh[16][4096][256] + xl  (64 MB); OTh/OTl OVERLAY after v-GEMM
#define O_XSL   46203136
#define O_V     79757568   // float[16][4096][256] (64 MB)
// end = 146866432 (~140 MB)

__device__ __forceinline__ uint bfr(float f){          // fp32 -> bf16 bits, RNE
  uint u = __float_as_uint(f);
  return (u + 0x7FFFu + ((u >> 16) & 1u)) >> 16;
}
__device__ __forceinline__ float bff(uint h){ return __uint_as_float(h << 16); }

// ---------------- weight transpose (fp32, for fp64 centers kernel) ----------------
__global__ void k_transpose(const float* __restrict__ fw, const float* __restrict__ vw,
                            float* __restrict__ fwT, float* __restrict__ vwT){
  int id = blockIdx.x * 256 + threadIdx.x;
  int mat = id >> 16; int rem = id & 65535;
  int j = rem >> 8, c = rem & 255;
  const float* src = (mat == 0) ? fw : vw;
  float* dst = (mat == 0) ? fwT : vwT;
  dst[c * 256 + j] = src[j * 256 + c];
}

// ---------------- weight bf16 hi/lo split ----------------
__global__ void k_wsplit(const float* __restrict__ fw, const float* __restrict__ vw,
                         const float* __restrict__ pw,
                         ushort* __restrict__ fh, ushort* __restrict__ fl,
                         ushort* __restrict__ vh, ushort* __restrict__ vl,
                         ushort* __restrict__ ph, ushort* __restrict__ pl){
  int id = blockIdx.x * 256 + threadIdx.x;   // 3*65536
  int mat = id >> 16, rem = id & 65535;
  const float* s = (mat == 0) ? fw : ((mat == 1) ? vw : pw);
  ushort* dh = (mat == 0) ? fh : ((mat == 1) ? vh : ph);
  ushort* dl = (mat == 0) ? fl : ((mat == 1) ? vl : pl);
  float a = s[rem];
  uint h = bfr(a);
  dh[rem] = (ushort)h;
  dl[rem] = (ushort)bfr(a - bff(h));
}

// ---------------- x bf16 hi/lo split: [t][b][c] fp32 -> [b][t][c] bf16 x2 ----------------
__global__ __launch_bounds__(256, 8) void k_xsplit(
    const float* __restrict__ x, ushort* __restrict__ xh, ushort* __restrict__ xl){
  size_t gid = (size_t)blockIdx.x * 256 + threadIdx.x;   // 4.19M threads
  size_t o = gid * 4;                                    // elem idx in [b][t][c]
  int c = (int)(o & 255); size_t bt = o >> 8;
  int t = (int)(bt & 4095); int b = (int)(bt >> 12);
  float4 a = *(const float4*)(x + ((size_t)t * B_SZ + b) * CIN + c);
  uint h0 = bfr(a.x), h1 = bfr(a.y), h2 = bfr(a.z), h3 = bfr(a.w);
  uint l0 = bfr(a.x - bff(h0)), l1 = bfr(a.y - bff(h1));
  uint l2 = bfr(a.z - bff(h2)), l3 = bfr(a.w - bff(h3));
  *(uint2*)(xh + o) = make_uint2(h0 | (h1 << 16), h2 | (h3 << 16));
  *(uint2*)(xl + o) = make_uint2(l0 | (l1 << 16), l2 | (l3 << 16));
}

// ---------------- fp64 spatial pooling of x ----------------
__global__ void k_pool(const float* __restrict__ x, double* __restrict__ px){
  int b = blockIdx.x >> 4, m = blockIdx.x & 15;
  int pr = m >> 2, pc = m & 3;
  int c = threadIdx.x;
  double s = 0.0;
  for (int i = 0; i < 16; i++){
    int t0 = (pr * 16 + i) * 64 + pc * 16;
    const float* xr = x + ((size_t)t0 * B_SZ + b) * CIN + c;
    for (int jj = 0; jj < 16; jj++)
      s += (double)xr[(size_t)jj * B_SZ * CIN];
  }
  px[(size_t)(b * 16 + m) * 256 + c] = s * (1.0 / 256.0);
}

// ---------------- fp64 centers + value centers ----------------
__global__ void k_centers(const double* __restrict__ px, const float* __restrict__ fwT,
                          const float* __restrict__ vwT, const float* __restrict__ fb,
                          const float* __restrict__ vb, double* __restrict__ c64,
                          float* __restrict__ c32, float* __restrict__ vc){
  int b = blockIdx.x >> 4, m = blockIdx.x & 15;
  int j = threadIdx.x;
  const double* pxr = px + (size_t)(b * 16 + m) * 256;
  double cq = (double)fb[j], cv = (double)vb[j];
  for (int c = 0; c < 256; c++){
    double p = pxr[c];
    cq += p * (double)fwT[c * 256 + j];
    cv += p * (double)vwT[c * 256 + j];
  }
  __shared__ double sq[256];
  __shared__ double snm[8];
  sq[j] = cq * cq;
  __syncthreads();
  int h = j >> 5, d = j & 31;
  if ((j & 31) == 0){
    double ts = 0.0;
    for (int dd = 0; dd < 32; dd++) ts += sq[h * 32 + dd];
    snm[h] = fmax(sqrt(ts), 1e-12);
  }
  __syncthreads();
  double nm = snm[h];
  size_t o = ((size_t)(b * N_H + h) * M_C + m) * D_H + d;
  double ch = cq / nm;
  c64[o] = ch; c32[o] = (float)ch; vc[o] = (float)cv;
}

// ======== MFMA GEMM core v2: 128x128 tile, K=256, BK=32, all-bf16 async staging ========
// LDS per tile: [kchunk(4)][row(128)][8 ushorts] = 8 KB, fragment-contiguous (no padding,
// conflict-free b128 reads, satisfies global_load_lds lane-contiguity).
#define TSZU 4096   // ushorts per tile

__device__ __forceinline__ void stage_async(
    const ushort* __restrict__ Ahg, const ushort* __restrict__ Alg, size_t aRow0,
    const ushort* __restrict__ Bhg, const ushort* __restrict__ Blg, int bRow0,
    int kk, ushort* SM, int tid){
  int w = tid >> 6, lane = tid & 63;
  const ushort* src = (w == 0) ? Ahg : (w == 1) ? Alg : (w == 2) ? Bhg : Blg;
  size_t row0 = (w < 2) ? aRow0 : (size_t)bRow0;
  ushort* dst = SM + w * TSZU;
#pragma unroll
  for (int j = 0; j < 8; j++){
    int kchunk = j >> 1, rh = j & 1;
    const ushort* g = src + (row0 + (size_t)(rh * 64 + lane)) * 256 + kk * 32 + kchunk * 8;
    ushort* l = dst + (kchunk * 128 + rh * 64) * 8;
    __builtin_amdgcn_global_load_lds((const __attribute__((address_space(1))) void*)g,
                                     (__attribute__((address_space(3))) void*)l, 16, 0, 0);
  }
}

__device__ __forceinline__ void compute_step(
    const ushort* SM, int wm, int wn, int li, int quad, frag_c acc[4][4]){
  const ushort* Ah = SM;            const ushort* Al = SM + TSZU;
  const ushort* Bh = SM + 2*TSZU;   const ushort* Bl = SM + 3*TSZU;
  frag_ab ah[4], al[4], bh[4], bl[4];
#pragma unroll
  for (int m = 0; m < 4; m++){
    int off = (quad * 128 + wm * 64 + m * 16 + li) * 8;
    ah[m] = *(const frag_ab*)&Ah[off];
    al[m] = *(const frag_ab*)&Al[off];
  }
#pragma unroll
  for (int n = 0; n < 4; n++){
    int off = (quad * 128 + wn * 64 + n * 16 + li) * 8;
    bh[n] = *(const frag_ab*)&Bh[off];
    bl[n] = *(const frag_ab*)&Bl[off];
  }
#pragma unroll
  for (int m = 0; m < 4; m++)
#pragma unroll
    for (int n = 0; n < 4; n++){
      acc[m][n] = __builtin_amdgcn_mfma_f32_16x16x32_bf16(ah[m], bh[n], acc[m][n], 0, 0, 0);
      acc[m][n] = __builtin_amdgcn_mfma_f32_16x16x32_bf16(ah[m], bl[n], acc[m][n], 0, 0, 0);
      acc[m][n] = __builtin_amdgcn_mfma_f32_16x16x32_bf16(al[m], bh[n], acc[m][n], 0, 0, 0);
    }
}

__device__ __forceinline__ void gemm_core(
    const ushort* __restrict__ Ahg, const ushort* __restrict__ Alg, size_t aRow0,
    const ushort* __restrict__ Bhg, const ushort* __restrict__ Blg, int bRow0,
    ushort* SM, frag_c acc[4][4], int tid){
  int li = tid & 15, quad = (tid & 63) >> 4;
  int w = tid >> 6, wm = w >> 1, wn = w & 1;
#pragma unroll
  for (int m = 0; m < 4; m++)
#pragma unroll
    for (int n = 0; n < 4; n++)
      acc[m][n] = frag_c{0.f, 0.f, 0.f, 0.f};
  for (int kk = 0; kk < 8; kk++){
    __syncthreads();
    stage_async(Ahg, Alg, aRow0, Bhg, Blg, bRow0, kk, SM, tid);
    __syncthreads();
    compute_step(SM, wm, wn, li, quad, acc);
  }
}

// ---------------- GEMM + plain store (v-GEMM and proj-GEMM) ----------------
// A global: bf16 [b][4096][256]; Out fp32 at row*oStride + b*oBMul + col
__global__ __launch_bounds__(256, 3) void k_gemm_store(
    const ushort* __restrict__ Ahg, const ushort* __restrict__ Alg,
    const ushort* __restrict__ Bh, const ushort* __restrict__ Bl,
    const float* __restrict__ bias,
    float* __restrict__ Out, int oStride, int oBMul){
  int bx = blockIdx.x;
  int nt = bx & 1, mt = (bx >> 1) & 31, b = bx >> 6;
  __shared__ ushort SM[4 * TSZU];
  frag_c acc[4][4];
  int tid = threadIdx.x;
  gemm_core(Ahg, Alg, (size_t)b * 4096 + mt * 128, Bh, Bl, nt * 128, SM, acc, tid);

  int li = tid & 15, quad = (tid & 63) >> 4;
  int w = tid >> 6, wm = w >> 1, wn = w & 1;
  int colBase = nt * 128 + wn * 64 + li;
  float bn[4];
#pragma unroll
  for (int n = 0; n < 4; n++) bn[n] = bias[colBase + n * 16];
#pragma unroll
  for (int m = 0; m < 4; m++){
    int row0 = mt * 128 + wm * 64 + m * 16 + quad * 4;
#pragma unroll
    for (int n = 0; n < 4; n++){
      int col = colBase + n * 16;
#pragma unroll
      for (int r = 0; r < 4; r++)
        Out[(size_t)(row0 + r) * oStride + (size_t)b * oBMul + col] = acc[m][n][r] + bn[n];
    }
  }
}

// ---------------- GEMM + fused similarity/top-2 epilogue (q path) ----------------
__global__ __launch_bounds__(256, 2) void k_gemm_qsim(
    const ushort* __restrict__ Ahg, const ushort* __restrict__ Alg,
    const ushort* __restrict__ Bh, const ushort* __restrict__ Bl,
    const float* __restrict__ bias, const float* __restrict__ c32,
    const float* __restrict__ salpha, const float* __restrict__ sbeta,
    u8* __restrict__ selm, float2* __restrict__ selw,
    int* __restrict__ cnt, unsigned int* __restrict__ list){
  int bx = blockIdx.x;
  int nt = bx & 1, mt = (bx >> 1) & 31, b = bx >> 6;
  __shared__ ushort SM[16896];    // 33792 B: 4 tiles (32768) / qbuf 64x132 fp32 overlay
  __shared__ float cs[4][520];    // this block's 4 heads' normalized centers
  frag_c acc[4][4];
  int tid = threadIdx.x;
  for (int i = tid; i < 2048; i += 256){
    int hh = i >> 9, rem = i & 511;
    cs[hh][rem] = c32[(size_t)b * 4096 + (nt * 4 + hh) * 512 + rem];
  }
  gemm_core(Ahg, Alg, (size_t)b * 4096 + mt * 128, Bh, Bl, nt * 128, SM, acc, tid);

  int li = tid & 15, quad = (tid & 63) >> 4;
  int w = tid >> 6, wm = w >> 1, wn = w & 1;
  int colBase = nt * 128 + wn * 64 + li;
  float bn[4];
#pragma unroll
  for (int n = 0; n < 4; n++) bn[n] = bias[colBase + n * 16];
  float alpha = salpha[0], beta = sbeta[0];
  float* qbuf = (float*)SM;
  for (int half = 0; half < 2; half++){
    __syncthreads();
    if (wm == half){
#pragma unroll
      for (int m = 0; m < 4; m++)
#pragma unroll
        for (int n = 0; n < 4; n++)
#pragma unroll
          for (int r = 0; r < 4; r++)
            qbuf[(m * 16 + quad * 4 + r) * 132 + wn * 64 + n * 16 + li] = acc[m][n][r] + bn[n];
    }
    __syncthreads();
    int tok = tid >> 2, hh = tid & 3;
    int t = mt * 128 + half * 64 + tok;
    int h = nt * 4 + hh;
    float q[32];
    float ss = 0.f;
#pragma unroll
    for (int d = 0; d < 32; d += 4){
      float4 qv = *(const float4*)&qbuf[tok * 132 + hh * 32 + d];
      q[d] = qv.x; q[d + 1] = qv.y; q[d + 2] = qv.z; q[d + 3] = qv.w;
      ss += qv.x * qv.x + qv.y * qv.y + qv.z * qv.z + qv.w * qv.w;
    }
    float inv = 1.f / fmaxf(sqrtf(ss), 1e-12f);
    float s1 = -1e30f, s2 = -1e30f, s3 = -1e30f; int i1 = 0, i2 = 0;
#pragma unroll
    for (int m = 0; m < 16; m++){
      float dot = 0.f;
#pragma unroll
      for (int d = 0; d < 32; d += 4){
        float4 cv = *(const float4*)&cs[hh][m * 32 + d];
        dot = fmaf(q[d], cv.x, fmaf(q[d + 1], cv.y, fmaf(q[d + 2], cv.z, fmaf(q[d + 3], cv.w, dot))));
      }
      float z = beta + alpha * (dot * inv);
      float s = 1.f / (1.f + expf(-z));
      if (s > s1){ s3 = s2; s2 = s1; i2 = i1; s1 = s; i1 = m; }
      else if (s > s2){ s3 = s2; s2 = s; i2 = m; }
      else if (s > s3){ s3 = s; }
    }
    if (s2 - s3 < TAU){
      int idx = atomicAdd(cnt, 1);
      if (idx < RCAP) list[idx] = (((unsigned)(b * N_H + h)) << 12) | (unsigned)t;
    }
    float r1 = s1 * s1, r2 = s2 * s2;
    float den = r1 + r2 + 1e-6f;
    size_t so = (size_t)(b * N_H + h) * T_SZ + t;
    selm[so * 2] = (u8)i1; selm[so * 2 + 1] = (u8)i2;
    selw[so] = make_float2(r1 / den, r2 / den);
  }
}

// ---------------- fp64 rescue for near-tie tokens: ONE WAVE PER TOKEN ----------------
__global__ __launch_bounds__(256, 4) void k_rescue(
    const float* __restrict__ x, const float* __restrict__ fw, const float* __restrict__ fb,
    const double* __restrict__ c64, const float* __restrict__ salpha, const float* __restrict__ sbeta,
    const int* __restrict__ cnt, const unsigned int* __restrict__ list,
    u8* __restrict__ selm, float2* __restrict__ selw){
  int n = *cnt; if (n > RCAP) n = RCAP;
  int lane = threadIdx.x & 63;
  int wid = (blockIdx.x * 256 + threadIdx.x) >> 6;
  int nw = gridDim.x * 4;
  double alpha = (double)salpha[0], beta = (double)sbeta[0];
  for (int i = wid; i < n; i += nw){
    unsigned e = list[i];
    int t = e & 4095; int bh = e >> 12; int b = bh >> 3, h = bh & 7;
    int d = lane & 31, half = lane >> 5;
    const float* xh = x + ((size_t)t * B_SZ + b) * CIN + half * 128;
    const float* wr = fw + (size_t)(h * 32 + d) * CIN + half * 128;
    double a0 = 0, a1 = 0, a2 = 0, a3 = 0;
#pragma unroll 4
    for (int c = 0; c < 128; c += 4){
      float4 xv = *(const float4*)(xh + c);
      float4 wv = *(const float4*)(wr + c);
      a0 += (double)xv.x * (double)wv.x;
      a1 += (double)xv.y * (double)wv.y;
      a2 += (double)xv.z * (double)wv.z;
      a3 += (double)xv.w * (double)wv.w;
    }
    double qd = (a0 + a1) + (a2 + a3);
    qd += __shfl_down(qd, 32);
    if (lane < 32) qd += (double)fb[h * 32 + d];
    else qd = 0.0;
    double ss = qd * qd;
#pragma unroll
    for (int off = 32; off; off >>= 1) ss += __shfl_xor(ss, off);
    double inv = 1.0 / fmax(sqrt(ss), 1e-12);
    const double* cb = c64 + (size_t)bh * (M_C * D_H);
    int m = lane & 15;
    double dot = 0.0;
#pragma unroll
    for (int dd = 0; dd < 32; dd++){
      double qv = __shfl(qd, dd);
      dot += qv * cb[m * 32 + dd];
    }
    double z = beta + alpha * (dot * inv);
    double s = 1.0 / (1.0 + exp(-z));
    double s1 = -1e300, s2 = -1e300; int i1 = 0, i2 = 0;
#pragma unroll
    for (int mm = 0; mm < 16; mm++){
      double sv = __shfl(s, mm);
      if (sv > s1){ s2 = s1; i2 = i1; s1 = sv; i1 = mm; }
      else if (sv > s2){ s2 = sv; i2 = mm; }
    }
    if (lane == 0){
      double r1 = s1 * s1, r2 = s2 * s2, den = r1 + r2 + 1e-6;
      size_t so = (size_t)bh * T_SZ + t;
      selm[so * 2] = (u8)i1; selm[so * 2 + 1] = (u8)i2;
      selw[so] = make_float2((float)(r1 / den), (float)(r2 / den));
    }
  }
}

// ---------------- scatter: ownership-transposed, NO atomics ----------------
__global__ __launch_bounds__(256, 4) void k_scatter(
    const float* __restrict__ v, const u8* __restrict__ selm, const float2* __restrict__ selw,
    float* __restrict__ gpart){
  int bh = blockIdx.x >> 3, chunk = blockIdx.x & 7;
  int b = bh >> 3, h = bh & 7;
  int tid = threadIdx.x;
  int mA = tid >> 5, mB = mA + 8, d = tid & 31;
  __shared__ uchar2 sm[512];
  __shared__ float2 sw[512];
  for (int i = tid; i < 512; i += 256){
    size_t so = (size_t)bh * T_SZ + chunk * 512 + i;
    sm[i] = make_uchar2(selm[so * 2], selm[so * 2 + 1]);
    sw[i] = selw[so];
  }
  __syncthreads();
  const float* vb = v + ((size_t)b * T_SZ + chunk * 512) * CIN + h * 32 + d;
  float accA = 0.f, accB = 0.f, cntA = 0.f, cntB = 0.f;
#pragma unroll 8
  for (int i = 0; i < 512; i++){
    float vv = vb[(size_t)i * CIN];
    uchar2 mm = sm[i];
    float2 w = sw[i];
    float wA = (mm.x == mA) ? w.x : ((mm.y == mA) ? w.y : 0.f);
    float wB = (mm.x == mB) ? w.x : ((mm.y == mB) ? w.y : 0.f);
    accA = fmaf(wA, vv, accA); cntA += wA;
    accB = fmaf(wB, vv, accB); cntB += wB;
  }
  float* gp = gpart + (size_t)(bh * 8 + chunk) * 528;
  gp[mA * 33 + d] = accA;
  gp[mB * 33 + d] = accB;
  if (d == 0){ gp[mA * 33 + 32] = cntA; gp[mB * 33 + 32] = cntB; }
}

// ---------------- centers_out finalize ----------------
__global__ void k_cfinal(const float* __restrict__ gpart, const float* __restrict__ vc,
                         float* __restrict__ cout){
  int id = blockIdx.x * 256 + threadIdx.x;
  int bh = id >> 9, rem = id & 511, m = rem >> 5, d = rem & 31;
  float num = 0.f, den = 0.f;
#pragma unroll
  for (int c = 0; c < 8; c++){
    const float* gp = gpart + (size_t)(bh * 8 + c) * 528 + m * 33;
    num += gp[d];
    den += gp[32];
  }
  cout[id] = (num + vc[id]) / (den + 1.0f);
}

// ---------------- build out_tok, pre-split bf16 [b][t][c] ----------------
__global__ __launch_bounds__(256, 4) void k_mix(
    const float* __restrict__ cout, const u8* __restrict__ selm, const float2* __restrict__ selw,
    ushort* __restrict__ OTh, ushort* __restrict__ OTl){
  int b = blockIdx.x >> 7, tt = blockIdx.x & 127;
  __shared__ float cs[8][516];
  int tid = threadIdx.x;
  for (int k = 0; k < 16; k++){
    int i = k * 256 + tid;
    cs[i >> 9][i & 511] = cout[(size_t)b * 4096 + i];
  }
  __syncthreads();
  int r = tid >> 3, h = tid & 7;
  int t = tt * 32 + r;
  size_t so = (size_t)(b * N_H + h) * T_SZ + t;
  int m1 = selm[so * 2], m2 = selm[so * 2 + 1];
  float2 w = selw[so];
#pragma unroll
  for (int d = 0; d < 32; d += 4){
    float4 c1 = *(const float4*)&cs[h][m1 * 32 + d];
    float4 c2 = *(const float4*)&cs[h][m2 * 32 + d];
    float4 o = make_float4(w.x * c1.x + w.y * c2.x, w.x * c1.y + w.y * c2.y,
                           w.x * c1.z + w.y * c2.z, w.x * c1.w + w.y * c2.w);
    uint h0 = bfr(o.x), h1 = bfr(o.y), h2 = bfr(o.z), h3 = bfr(o.w);
    uint l0 = bfr(o.x - bff(h0)), l1 = bfr(o.y - bff(h1));
    uint l2 = bfr(o.z - bff(h2)), l3 = bfr(o.w - bff(h3));
    size_t oo = ((size_t)b * T_SZ + t) * CIN + h * 32 + d;
    *(uint2*)(OTh + oo) = make_uint2(h0 | (h1 << 16), h2 | (h3 << 16));
    *(uint2*)(OTl + oo) = make_uint2(l0 | (l1 << 16), l2 | (l3 << 16));
  }
}

extern "C" void kernel_launch(void* const* d_in, const int* in_sizes, int n_in,
                              void* d_out, int out_size, void* d_ws, size_t ws_size,
                              hipStream_t stream) {
  const float* x   = (const float*)d_in[0];
  const float* f_w = (const float*)d_in[1];
  const float* f_b = (const float*)d_in[2];
  const float* v_w = (const float*)d_in[3];
  const float* v_b = (const float*)d_in[4];
  const float* p_w = (const float*)d_in[5];
  const float* p_b = (const float*)d_in[6];
  const float* s_a = (const float*)d_in[7];
  const float* s_b = (const float*)d_in[8];
  float* out = (float*)d_out;
  char* ws = (char*)d_ws;

  float*  fwT  = (float*)(ws + O_FWT);
  float*  vwT  = (float*)(ws + O_VWT);
  ushort* wfh  = (ushort*)(ws + O_WFH);
  ushort* wfl  = (ushort*)(ws + O_WFL);
  ushort* wvh  = (ushort*)(ws + O_WVH);
  ushort* wvl  = (ushort*)(ws + O_WVL);
  ushort* wph  = (ushort*)(ws + O_WPH);
  ushort* wpl  = (ushort*)(ws + O_WPL);
  double* px   = (double*)(ws + O_PX);
  double* c64  = (double*)(ws + O_C64);
  float*  c32  = (float*)(ws + O_C32);
  float*  vc   = (float*)(ws + O_VC);
  float*  cout = (float*)(ws + O_COUT);
  float*  gpart= (float*)(ws + O_GPART);
  int*    cnt  = (int*)(ws + O_CNT);
  unsigned int* list = (unsigned int*)(ws + O_LIST);
  u8*     selm = (u8*)(ws + O_SELM);
  float2* selw = (float2*)(ws + O_SELW);
  ushort* xh   = (ushort*)(ws + O_XS);
  ushort* xl   = (ushort*)(ws + O_XSL);
  ushort* OTh  = (ushort*)(ws + O_XS);    // overlay: xsplit dead after v-GEMM
  ushort* OTl  = (ushort*)(ws + O_XSL);
  float*  v    = (float*)(ws + O_V);

  hipMemsetAsync(ws + O_CNT, 0, 256, stream);
  k_transpose<<<512, 256, 0, stream>>>(f_w, v_w, fwT, vwT);
  k_wsplit<<<768, 256, 0, stream>>>(f_w, v_w, p_w, wfh, wfl, wvh, wvl, wph, wpl);
  k_xsplit<<<16384, 256, 0, stream>>>(x, xh, xl);
  k_pool<<<256, 256, 0, stream>>>(x, px);
  k_centers<<<256, 256, 0, stream>>>(px, fwT, vwT, f_b, v_b, c64, c32, vc);
  k_gemm_qsim<<<1024, 256, 0, stream>>>(xh, xl, wfh, wfl, f_b, c32, s_a, s_b,
                                        selm, selw, cnt, list);
  // v-GEMM: out v[b][t][c]
  k_gemm_store<<<1024, 256, 0, stream>>>(xh, xl, wvh, wvl, v_b, v, 256, T_SZ * CIN);
  k_rescue<<<256, 256, 0, stream>>>(x, f_w, f_b, c64, s_a, s_b, cnt, list, selm, selw);
  k_scatter<<<1024, 256, 0, stream>>>(v, selm, selw, gpart);
  k_cfinal<<<256, 256, 0, stream>>>(gpart, vc, cout);
  k_mix<<<2048, 256, 0, stream>>>(cout, selm, selw, OTh, OTl);
  // proj-GEMM: A = OT split [b][t][c]; out [t][b][c]
  k_gemm_store<<<1024, 256, 0, stream>>>(OTh, OTl, wph, wpl, p_b, out, 4096, 256);
}

// Round 6
// 392.777 us; speedup vs baseline: 1.2692x; 1.2692x over previous
//
#include <hip/hip_runtime.h>
#include <math.h>

#define T_SZ 4096
#define B_SZ 16
#define CIN 256
#define N_H 8
#define D_H 32
#define M_C 16
#define TAU 5e-5f
#define RCAP (1<<19)

typedef unsigned char u8;
typedef unsigned int uint;
typedef unsigned short ushort;

using frag_ab = __attribute__((ext_vector_type(8))) short;   // 8 bf16 (4 VGPRs)
using frag_c  = __attribute__((ext_vector_type(4))) float;   // 4 fp32 acc

// ---- workspace layout (bytes) ----
// Permuted bf16 layout for GEMM operands: [tile][kk(8)][kchunk(4)][row(128)][8]
// = exactly the LDS order, so global_load_lds is lane-contiguous on both sides.
#define O_FWT   0          // float[256*256] f_w^T [c][j] (for k_centers)
#define O_VWT   262144     // float[256*256]
#define O_WFH   524288     // bf16 permuted weight splits (2 n-tiles)
#define O_WFL   655360
#define O_WVH   786432
#define O_WVL   917504
#define O_WPH   1048576
#define O_WPL   1179648
#define O_PX    1310720    // double[B*16*256]
#define O_C64   1835008    // double[128*16*32] normalized centers
#define O_C32   2359296    // float same
#define O_VC    2621440    // float value centers
#define O_COUT  2883584    // float centers_out
#define O_GPART 3145728    // float[128*8*528]
#define O_CNT   5308416    // int rescue counter
#define O_LIST  5308672    // uint[RCAP]
#define O_SELM  7405824    // u8[128*4096*2]
#define O_SELW  8454400    // float2[128*4096]
#define O_XS    12648704   // bf16 xh permuted [b*32 tiles][8][4][128][8] (32MB) ; OTh overlays
#define O_XSL   46203136   // xl / OTl
#define O_V     79757568   // float[16][4096][256] (64 MB)
// end = 146866432 (~140 MB)

__device__ __forceinline__ uint bfr(float f){          // fp32 -> bf16 bits, RNE
  uint u = __float_as_uint(f);
  return (u + 0x7FFFu + ((u >> 16) & 1u)) >> 16;
}
__device__ __forceinline__ float bff(uint h){ return __uint_as_float(h << 16); }

// ---------------- weight transpose (fp32, for fp64 centers kernel) ----------------
__global__ void k_transpose(const float* __restrict__ fw, const float* __restrict__ vw,
                            float* __restrict__ fwT, float* __restrict__ vwT){
  int id = blockIdx.x * 256 + threadIdx.x;
  int mat = id >> 16; int rem = id & 65535;
  int j = rem >> 8, c = rem & 255;
  const float* src = (mat == 0) ? fw : vw;
  float* dst = (mat == 0) ? fwT : vwT;
  dst[c * 256 + j] = src[j * 256 + c];
}

// ---------------- weight bf16 hi/lo split, PERMUTED tile layout ----------------
__global__ void k_wsplit(const float* __restrict__ fw, const float* __restrict__ vw,
                         const float* __restrict__ pw,
                         ushort* __restrict__ fh, ushort* __restrict__ fl,
                         ushort* __restrict__ vh, ushort* __restrict__ vl,
                         ushort* __restrict__ ph, ushort* __restrict__ pl){
  int id = blockIdx.x * 256 + threadIdx.x;   // 3*65536
  int mat = id >> 16, rem = id & 65535;
  const float* s = (mat == 0) ? fw : ((mat == 1) ? vw : pw);
  ushort* dh = (mat == 0) ? fh : ((mat == 1) ? vh : ph);
  ushort* dl = (mat == 0) ? fl : ((mat == 1) ? vl : pl);
  int n = rem >> 8, k = rem & 255;
  size_t po = ((size_t)((n >> 7) * 8 + (k >> 5))) * 4096
            + (size_t)(((k >> 3) & 3) * 128 + (n & 127)) * 8 + (k & 7);
  float a = s[rem];
  uint h = bfr(a);
  dh[po] = (ushort)h;
  dl[po] = (ushort)bfr(a - bff(h));
}

// ---------------- x bf16 hi/lo split -> PERMUTED tile layout ----------------
// block = (b, mt): one 128-row tile. Writes coalesced 16B/lane; reads L2-absorbed.
__global__ __launch_bounds__(256, 8) void k_xsplit(
    const float* __restrict__ x, ushort* __restrict__ xh, ushort* __restrict__ xl){
  int b = blockIdx.x >> 5, mt = blockIdx.x & 31;   // 512 blocks
  int row = threadIdx.x & 127, cg0 = threadIdx.x >> 7;  // 2 halves
  int t = mt * 128 + row;
  const float* xr = x + ((size_t)t * B_SZ + b) * CIN;
  size_t base = (size_t)(b * 32 + mt) * 8 * 4096;
#pragma unroll 4
  for (int i = 0; i < 16; i++){
    int c8 = i * 2 + cg0;                 // 32 chunks of 8 channels
    float4 a0 = *(const float4*)(xr + c8 * 8);
    float4 a1 = *(const float4*)(xr + c8 * 8 + 4);
    uint h0 = bfr(a0.x), h1 = bfr(a0.y), h2 = bfr(a0.z), h3 = bfr(a0.w);
    uint h4 = bfr(a1.x), h5 = bfr(a1.y), h6 = bfr(a1.z), h7 = bfr(a1.w);
    uint l0 = bfr(a0.x - bff(h0)), l1 = bfr(a0.y - bff(h1));
    uint l2 = bfr(a0.z - bff(h2)), l3 = bfr(a0.w - bff(h3));
    uint l4 = bfr(a1.x - bff(h4)), l5 = bfr(a1.y - bff(h5));
    uint l6 = bfr(a1.z - bff(h6)), l7 = bfr(a1.w - bff(h7));
    size_t off = base + (size_t)(c8 >> 2) * 4096 + (size_t)((c8 & 3) * 128 + row) * 8;
    *(uint4*)(xh + off) = make_uint4(h0 | (h1 << 16), h2 | (h3 << 16), h4 | (h5 << 16), h6 | (h7 << 16));
    *(uint4*)(xl + off) = make_uint4(l0 | (l1 << 16), l2 | (l3 << 16), l4 | (l5 << 16), l6 | (l7 << 16));
  }
}

// ---------------- fp64 spatial pooling of x ----------------
__global__ void k_pool(const float* __restrict__ x, double* __restrict__ px){
  int b = blockIdx.x >> 4, m = blockIdx.x & 15;
  int pr = m >> 2, pc = m & 3;
  int c = threadIdx.x;
  double s = 0.0;
  for (int i = 0; i < 16; i++){
    int t0 = (pr * 16 + i) * 64 + pc * 16;
    const float* xr = x + ((size_t)t0 * B_SZ + b) * CIN + c;
    for (int jj = 0; jj < 16; jj++)
      s += (double)xr[(size_t)jj * B_SZ * CIN];
  }
  px[(size_t)(b * 16 + m) * 256 + c] = s * (1.0 / 256.0);
}

// ---------------- fp64 centers + value centers ----------------
__global__ void k_centers(const double* __restrict__ px, const float* __restrict__ fwT,
                          const float* __restrict__ vwT, const float* __restrict__ fb,
                          const float* __restrict__ vb, double* __restrict__ c64,
                          float* __restrict__ c32, float* __restrict__ vc){
  int b = blockIdx.x >> 4, m = blockIdx.x & 15;
  int j = threadIdx.x;
  const double* pxr = px + (size_t)(b * 16 + m) * 256;
  double cq = (double)fb[j], cv = (double)vb[j];
  for (int c = 0; c < 256; c++){
    double p = pxr[c];
    cq += p * (double)fwT[c * 256 + j];
    cv += p * (double)vwT[c * 256 + j];
  }
  __shared__ double sq[256];
  __shared__ double snm[8];
  sq[j] = cq * cq;
  __syncthreads();
  int h = j >> 5, d = j & 31;
  if ((j & 31) == 0){
    double ts = 0.0;
    for (int dd = 0; dd < 32; dd++) ts += sq[h * 32 + dd];
    snm[h] = fmax(sqrt(ts), 1e-12);
  }
  __syncthreads();
  double nm = snm[h];
  size_t o = ((size_t)(b * N_H + h) * M_C + m) * D_H + d;
  double ch = cq / nm;
  c64[o] = ch; c32[o] = (float)ch; vc[o] = (float)cv;
}

// ======== MFMA GEMM core v3: permuted-global async staging, fully coalesced ========
#define TSZU 4096   // ushorts per LDS tile

__device__ __forceinline__ void stage_async(
    const ushort* __restrict__ At_h, const ushort* __restrict__ At_l,
    const ushort* __restrict__ Bt_h, const ushort* __restrict__ Bt_l,
    int kk, ushort* SM, int tid){
  int w = tid >> 6, lane = tid & 63;
  const ushort* src = (w == 0) ? At_h : (w == 1) ? At_l : (w == 2) ? Bt_h : Bt_l;
  ushort* dst = SM + w * TSZU;
  const ushort* g0 = src + (size_t)kk * 4096 + lane * 8;
#pragma unroll
  for (int j = 0; j < 8; j++){
    __builtin_amdgcn_global_load_lds(
        (const __attribute__((address_space(1))) void*)(g0 + j * 512),
        (__attribute__((address_space(3))) void*)(dst + j * 512), 16, 0, 0);
  }
}

__device__ __forceinline__ void compute_step(
    const ushort* SM, int wm, int wn, int li, int quad, frag_c acc[4][4]){
  const ushort* Ah = SM;            const ushort* Al = SM + TSZU;
  const ushort* Bh = SM + 2*TSZU;   const ushort* Bl = SM + 3*TSZU;
  frag_ab ah[4], al[4], bh[4], bl[4];
#pragma unroll
  for (int m = 0; m < 4; m++){
    int off = (quad * 128 + wm * 64 + m * 16 + li) * 8;
    ah[m] = *(const frag_ab*)&Ah[off];
    al[m] = *(const frag_ab*)&Al[off];
  }
#pragma unroll
  for (int n = 0; n < 4; n++){
    int off = (quad * 128 + wn * 64 + n * 16 + li) * 8;
    bh[n] = *(const frag_ab*)&Bh[off];
    bl[n] = *(const frag_ab*)&Bl[off];
  }
#pragma unroll
  for (int m = 0; m < 4; m++)
#pragma unroll
    for (int n = 0; n < 4; n++){
      acc[m][n] = __builtin_amdgcn_mfma_f32_16x16x32_bf16(ah[m], bh[n], acc[m][n], 0, 0, 0);
      acc[m][n] = __builtin_amdgcn_mfma_f32_16x16x32_bf16(ah[m], bl[n], acc[m][n], 0, 0, 0);
      acc[m][n] = __builtin_amdgcn_mfma_f32_16x16x32_bf16(al[m], bh[n], acc[m][n], 0, 0, 0);
    }
}

__device__ __forceinline__ void gemm_core(
    const ushort* __restrict__ At_h, const ushort* __restrict__ At_l,
    const ushort* __restrict__ Bt_h, const ushort* __restrict__ Bt_l,
    ushort* SM, frag_c acc[4][4], int tid){
  int li = tid & 15, quad = (tid & 63) >> 4;
  int w = tid >> 6, wm = w >> 1, wn = w & 1;
#pragma unroll
  for (int m = 0; m < 4; m++)
#pragma unroll
    for (int n = 0; n < 4; n++)
      acc[m][n] = frag_c{0.f, 0.f, 0.f, 0.f};
  for (int kk = 0; kk < 8; kk++){
    __syncthreads();
    stage_async(At_h, At_l, Bt_h, Bt_l, kk, SM, tid);
    __syncthreads();
    compute_step(SM, wm, wn, li, quad, acc);
  }
}

// ---------------- GEMM + plain store (v-GEMM and proj-GEMM) ----------------
__global__ __launch_bounds__(256, 4) void k_gemm_store(
    const ushort* __restrict__ Ahg, const ushort* __restrict__ Alg,
    const ushort* __restrict__ Bh, const ushort* __restrict__ Bl,
    const float* __restrict__ bias,
    float* __restrict__ Out, int oStride, int oBMul){
  int bx = blockIdx.x;
  int nt = bx & 1, mt = (bx >> 1) & 31, b = bx >> 6;
  __shared__ ushort SM[4 * TSZU];
  frag_c acc[4][4];
  int tid = threadIdx.x;
  size_t aOff = (size_t)(b * 32 + mt) * 8 * 4096;
  size_t bOff = (size_t)nt * 8 * 4096;
  gemm_core(Ahg + aOff, Alg + aOff, Bh + bOff, Bl + bOff, SM, acc, tid);

  int li = tid & 15, quad = (tid & 63) >> 4;
  int w = tid >> 6, wm = w >> 1, wn = w & 1;
  int colBase = nt * 128 + wn * 64 + li;
  float bn[4];
#pragma unroll
  for (int n = 0; n < 4; n++) bn[n] = bias[colBase + n * 16];
#pragma unroll
  for (int m = 0; m < 4; m++){
    int row0 = mt * 128 + wm * 64 + m * 16 + quad * 4;
#pragma unroll
    for (int n = 0; n < 4; n++){
      int col = colBase + n * 16;
#pragma unroll
      for (int r = 0; r < 4; r++)
        Out[(size_t)(row0 + r) * oStride + (size_t)b * oBMul + col] = acc[m][n][r] + bn[n];
    }
  }
}

// ---------------- GEMM + fused similarity/top-2 epilogue (q path) ----------------
__global__ __launch_bounds__(256, 3) void k_gemm_qsim(
    const ushort* __restrict__ Ahg, const ushort* __restrict__ Alg,
    const ushort* __restrict__ Bh, const ushort* __restrict__ Bl,
    const float* __restrict__ bias, const float* __restrict__ c32,
    const float* __restrict__ salpha, const float* __restrict__ sbeta,
    u8* __restrict__ selm, float2* __restrict__ selw,
    int* __restrict__ cnt, unsigned int* __restrict__ list){
  int bx = blockIdx.x;
  int nt = bx & 1, mt = (bx >> 1) & 31, b = bx >> 6;
  __shared__ ushort SM[16896];    // 33792 B: 4 tiles (32768 B) / qbuf 64x132 fp32 overlay
  __shared__ float cs[4][520];
  frag_c acc[4][4];
  int tid = threadIdx.x;
  for (int i = tid; i < 2048; i += 256){
    int hh = i >> 9, rem = i & 511;
    cs[hh][rem] = c32[(size_t)b * 4096 + (nt * 4 + hh) * 512 + rem];
  }
  size_t aOff = (size_t)(b * 32 + mt) * 8 * 4096;
  size_t bOff = (size_t)nt * 8 * 4096;
  gemm_core(Ahg + aOff, Alg + aOff, Bh + bOff, Bl + bOff, SM, acc, tid);

  int li = tid & 15, quad = (tid & 63) >> 4;
  int w = tid >> 6, wm = w >> 1, wn = w & 1;
  int colBase = nt * 128 + wn * 64 + li;
  float bn[4];
#pragma unroll
  for (int n = 0; n < 4; n++) bn[n] = bias[colBase + n * 16];
  float alpha = salpha[0], beta = sbeta[0];
  float* qbuf = (float*)SM;
  for (int half = 0; half < 2; half++){
    __syncthreads();
    if (wm == half){
#pragma unroll
      for (int m = 0; m < 4; m++)
#pragma unroll
        for (int n = 0; n < 4; n++)
#pragma unroll
          for (int r = 0; r < 4; r++)
            qbuf[(m * 16 + quad * 4 + r) * 132 + wn * 64 + n * 16 + li] = acc[m][n][r] + bn[n];
    }
    __syncthreads();
    int tok = tid >> 2, hh = tid & 3;
    int t = mt * 128 + half * 64 + tok;
    int h = nt * 4 + hh;
    float q[32];
    float ss = 0.f;
#pragma unroll
    for (int d = 0; d < 32; d += 4){
      float4 qv = *(const float4*)&qbuf[tok * 132 + hh * 32 + d];
      q[d] = qv.x; q[d + 1] = qv.y; q[d + 2] = qv.z; q[d + 3] = qv.w;
      ss += qv.x * qv.x + qv.y * qv.y + qv.z * qv.z + qv.w * qv.w;
    }
    float inv = 1.f / fmaxf(sqrtf(ss), 1e-12f);
    float s1 = -1e30f, s2 = -1e30f, s3 = -1e30f; int i1 = 0, i2 = 0;
#pragma unroll
    for (int m = 0; m < 16; m++){
      float dot = 0.f;
#pragma unroll
      for (int d = 0; d < 32; d += 4){
        float4 cv = *(const float4*)&cs[hh][m * 32 + d];
        dot = fmaf(q[d], cv.x, fmaf(q[d + 1], cv.y, fmaf(q[d + 2], cv.z, fmaf(q[d + 3], cv.w, dot))));
      }
      float z = beta + alpha * (dot * inv);
      float s = 1.f / (1.f + expf(-z));
      if (s > s1){ s3 = s2; s2 = s1; i2 = i1; s1 = s; i1 = m; }
      else if (s > s2){ s3 = s2; s2 = s; i2 = m; }
      else if (s > s3){ s3 = s; }
    }
    if (s2 - s3 < TAU){
      int idx = atomicAdd(cnt, 1);
      if (idx < RCAP) list[idx] = (((unsigned)(b * N_H + h)) << 12) | (unsigned)t;
    }
    float r1 = s1 * s1, r2 = s2 * s2;
    float den = r1 + r2 + 1e-6f;
    size_t so = (size_t)(b * N_H + h) * T_SZ + t;
    selm[so * 2] = (u8)i1; selm[so * 2 + 1] = (u8)i2;
    selw[so] = make_float2(r1 / den, r2 / den);
  }
}

// ---------------- fp64 rescue for near-tie tokens: ONE WAVE PER TOKEN ----------------
__global__ __launch_bounds__(256, 4) void k_rescue(
    const float* __restrict__ x, const float* __restrict__ fw, const float* __restrict__ fb,
    const double* __restrict__ c64, const float* __restrict__ salpha, const float* __restrict__ sbeta,
    const int* __restrict__ cnt, const unsigned int* __restrict__ list,
    u8* __restrict__ selm, float2* __restrict__ selw){
  int n = *cnt; if (n > RCAP) n = RCAP;
  int lane = threadIdx.x & 63;
  int wid = (blockIdx.x * 256 + threadIdx.x) >> 6;
  int nw = gridDim.x * 4;
  double alpha = (double)salpha[0], beta = (double)sbeta[0];
  for (int i = wid; i < n; i += nw){
    unsigned e = list[i];
    int t = e & 4095; int bh = e >> 12; int b = bh >> 3, h = bh & 7;
    int d = lane & 31, half = lane >> 5;
    const float* xh = x + ((size_t)t * B_SZ + b) * CIN + half * 128;
    const float* wr = fw + (size_t)(h * 32 + d) * CIN + half * 128;
    double a0 = 0, a1 = 0, a2 = 0, a3 = 0;
#pragma unroll 4
    for (int c = 0; c < 128; c += 4){
      float4 xv = *(const float4*)(xh + c);
      float4 wv = *(const float4*)(wr + c);
      a0 += (double)xv.x * (double)wv.x;
      a1 += (double)xv.y * (double)wv.y;
      a2 += (double)xv.z * (double)wv.z;
      a3 += (double)xv.w * (double)wv.w;
    }
    double qd = (a0 + a1) + (a2 + a3);
    qd += __shfl_down(qd, 32);
    if (lane < 32) qd += (double)fb[h * 32 + d];
    else qd = 0.0;
    double ss = qd * qd;
#pragma unroll
    for (int off = 32; off; off >>= 1) ss += __shfl_xor(ss, off);
    double inv = 1.0 / fmax(sqrt(ss), 1e-12);
    const double* cb = c64 + (size_t)bh * (M_C * D_H);
    int m = lane & 15;
    double dot = 0.0;
#pragma unroll
    for (int dd = 0; dd < 32; dd++){
      double qv = __shfl(qd, dd);
      dot += qv * cb[m * 32 + dd];
    }
    double z = beta + alpha * (dot * inv);
    double s = 1.0 / (1.0 + exp(-z));
    double s1 = -1e300, s2 = -1e300; int i1 = 0, i2 = 0;
#pragma unroll
    for (int mm = 0; mm < 16; mm++){
      double sv = __shfl(s, mm);
      if (sv > s1){ s2 = s1; i2 = i1; s1 = sv; i1 = mm; }
      else if (sv > s2){ s2 = sv; i2 = mm; }
    }
    if (lane == 0){
      double r1 = s1 * s1, r2 = s2 * s2, den = r1 + r2 + 1e-6;
      size_t so = (size_t)bh * T_SZ + t;
      selm[so * 2] = (u8)i1; selm[so * 2 + 1] = (u8)i2;
      selw[so] = make_float2((float)(r1 / den), (float)(r2 / den));
    }
  }
}

// ---------------- scatter: ownership-transposed, NO atomics ----------------
__global__ __launch_bounds__(256, 4) void k_scatter(
    const float* __restrict__ v, const u8* __restrict__ selm, const float2* __restrict__ selw,
    float* __restrict__ gpart){
  int bh = blockIdx.x >> 3, chunk = blockIdx.x & 7;
  int b = bh >> 3, h = bh & 7;
  int tid = threadIdx.x;
  int mA = tid >> 5, mB = mA + 8, d = tid & 31;
  __shared__ uchar2 sm[512];
  __shared__ float2 sw[512];
  for (int i = tid; i < 512; i += 256){
    size_t so = (size_t)bh * T_SZ + chunk * 512 + i;
    sm[i] = make_uchar2(selm[so * 2], selm[so * 2 + 1]);
    sw[i] = selw[so];
  }
  __syncthreads();
  const float* vb = v + ((size_t)b * T_SZ + chunk * 512) * CIN + h * 32 + d;
  float accA = 0.f, accB = 0.f, cntA = 0.f, cntB = 0.f;
#pragma unroll 8
  for (int i = 0; i < 512; i++){
    float vv = vb[(size_t)i * CIN];
    uchar2 mm = sm[i];
    float2 w = sw[i];
    float wA = (mm.x == mA) ? w.x : ((mm.y == mA) ? w.y : 0.f);
    float wB = (mm.x == mB) ? w.x : ((mm.y == mB) ? w.y : 0.f);
    accA = fmaf(wA, vv, accA); cntA += wA;
    accB = fmaf(wB, vv, accB); cntB += wB;
  }
  float* gp = gpart + (size_t)(bh * 8 + chunk) * 528;
  gp[mA * 33 + d] = accA;
  gp[mB * 33 + d] = accB;
  if (d == 0){ gp[mA * 33 + 32] = cntA; gp[mB * 33 + 32] = cntB; }
}

// ---------------- centers_out finalize ----------------
__global__ void k_cfinal(const float* __restrict__ gpart, const float* __restrict__ vc,
                         float* __restrict__ cout){
  int id = blockIdx.x * 256 + threadIdx.x;
  int bh = id >> 9, rem = id & 511, m = rem >> 5, d = rem & 31;
  float num = 0.f, den = 0.f;
#pragma unroll
  for (int c = 0; c < 8; c++){
    const float* gp = gpart + (size_t)(bh * 8 + c) * 528 + m * 33;
    num += gp[d];
    den += gp[32];
  }
  cout[id] = (num + vc[id]) / (den + 1.0f);
}

// ---------------- build out_tok, pre-split bf16, PERMUTED tile layout ----------------
__global__ __launch_bounds__(256, 4) void k_mix(
    const float* __restrict__ cout, const u8* __restrict__ selm, const float2* __restrict__ selw,
    ushort* __restrict__ OTh, ushort* __restrict__ OTl){
  int b = blockIdx.x >> 7, tt = blockIdx.x & 127;
  __shared__ float cs[8][516];
  int tid = threadIdx.x;
  for (int kth = 0; kth < 16; kth++){
    int i = kth * 256 + tid;
    cs[i >> 9][i & 511] = cout[(size_t)b * 4096 + i];
  }
  __syncthreads();
  int r = tid & 31, h = tid >> 5;           // row-contiguous lanes -> coalesced 16B stores
  int t = tt * 32 + r;
  int mt = t >> 7, row = t & 127;
  size_t so = (size_t)(b * N_H + h) * T_SZ + t;
  int m1 = selm[so * 2], m2 = selm[so * 2 + 1];
  float2 w = selw[so];
  size_t base = ((size_t)(b * 32 + mt) * 8 + h) * 4096 + (size_t)row * 8;
#pragma unroll
  for (int d = 0; d < 32; d += 8){
    float4 c1a = *(const float4*)&cs[h][m1 * 32 + d];
    float4 c2a = *(const float4*)&cs[h][m2 * 32 + d];
    float4 c1b = *(const float4*)&cs[h][m1 * 32 + d + 4];
    float4 c2b = *(const float4*)&cs[h][m2 * 32 + d + 4];
    float o0 = w.x * c1a.x + w.y * c2a.x, o1 = w.x * c1a.y + w.y * c2a.y;
    float o2 = w.x * c1a.z + w.y * c2a.z, o3 = w.x * c1a.w + w.y * c2a.w;
    float o4 = w.x * c1b.x + w.y * c2b.x, o5 = w.x * c1b.y + w.y * c2b.y;
    float o6 = w.x * c1b.z + w.y * c2b.z, o7 = w.x * c1b.w + w.y * c2b.w;
    uint h0 = bfr(o0), h1 = bfr(o1), h2 = bfr(o2), h3 = bfr(o3);
    uint h4 = bfr(o4), h5 = bfr(o5), h6 = bfr(o6), h7 = bfr(o7);
    uint l0 = bfr(o0 - bff(h0)), l1 = bfr(o1 - bff(h1));
    uint l2 = bfr(o2 - bff(h2)), l3 = bfr(o3 - bff(h3));
    uint l4 = bfr(o4 - bff(h4)), l5 = bfr(o5 - bff(h5));
    uint l6 = bfr(o6 - bff(h6)), l7 = bfr(o7 - bff(h7));
    size_t off = base + (size_t)(d >> 3) * 1024;   // kchunk*128*8
    *(uint4*)(OTh + off) = make_uint4(h0 | (h1 << 16), h2 | (h3 << 16), h4 | (h5 << 16), h6 | (h7 << 16));
    *(uint4*)(OTl + off) = make_uint4(l0 | (l1 << 16), l2 | (l3 << 16), l4 | (l5 << 16), l6 | (l7 << 16));
  }
}

extern "C" void kernel_launch(void* const* d_in, const int* in_sizes, int n_in,
                              void* d_out, int out_size, void* d_ws, size_t ws_size,
                              hipStream_t stream) {
  const float* x   = (const float*)d_in[0];
  const float* f_w = (const float*)d_in[1];
  const float* f_b = (const float*)d_in[2];
  const float* v_w = (const float*)d_in[3];
  const float* v_b = (const float*)d_in[4];
  const float* p_w = (const float*)d_in[5];
  const float* p_b = (const float*)d_in[6];
  const float* s_a = (const float*)d_in[7];
  const float* s_b = (const float*)d_in[8];
  float* out = (float*)d_out;
  char* ws = (char*)d_ws;

  float*  fwT  = (float*)(ws + O_FWT);
  float*  vwT  = (float*)(ws + O_VWT);
  ushort* wfh  = (ushort*)(ws + O_WFH);
  ushort* wfl  = (ushort*)(ws + O_WFL);
  ushort* wvh  = (ushort*)(ws + O_WVH);
  ushort* wvl  = (ushort*)(ws + O_WVL);
  ushort* wph  = (ushort*)(ws + O_WPH);
  ushort* wpl  = (ushort*)(ws + O_WPL);
  double* px   = (double*)(ws + O_PX);
  double* c64  = (double*)(ws + O_C64);
  float*  c32  = (float*)(ws + O_C32);
  float*  vc   = (float*)(ws + O_VC);
  float*  cout = (float*)(ws + O_COUT);
  float*  gpart= (float*)(ws + O_GPART);
  int*    cnt  = (int*)(ws + O_CNT);
  unsigned int* list = (unsigned int*)(ws + O_LIST);
  u8*     selm = (u8*)(ws + O_SELM);
  float2* selw = (float2*)(ws + O_SELW);
  ushort* xh   = (ushort*)(ws + O_XS);
  ushort* xl   = (ushort*)(ws + O_XSL);
  ushort* OTh  = (ushort*)(ws + O_XS);    // overlay: xsplit dead after v-GEMM
  ushort* OTl  = (ushort*)(ws + O_XSL);
  float*  v    = (float*)(ws + O_V);

  hipMemsetAsync(ws + O_CNT, 0, 256, stream);
  k_transpose<<<512, 256, 0, stream>>>(f_w, v_w, fwT, vwT);
  k_wsplit<<<768, 256, 0, stream>>>(f_w, v_w, p_w, wfh, wfl, wvh, wvl, wph, wpl);
  k_xsplit<<<512, 256, 0, stream>>>(x, xh, xl);
  k_pool<<<256, 256, 0, stream>>>(x, px);
  k_centers<<<256, 256, 0, stream>>>(px, fwT, vwT, f_b, v_b, c64, c32, vc);
  k_gemm_qsim<<<1024, 256, 0, stream>>>(xh, xl, wfh, wfl, f_b, c32, s_a, s_b,
                                        selm, selw, cnt, list);
  // v-GEMM: out v[b][t][c]
  k_gemm_store<<<1024, 256, 0, stream>>>(xh, xl, wvh, wvl, v_b, v, 256, T_SZ * CIN);
  k_rescue<<<256, 256, 0, stream>>>(x, f_w, f_b, c64, s_a, s_b, cnt, list, selm, selw);
  k_scatter<<<1024, 256, 0, stream>>>(v, selm, selw, gpart);
  k_cfinal<<<256, 256, 0, stream>>>(gpart, vc, cout);
  k_mix<<<2048, 256, 0, stream>>>(cout, selm, selw, OTh, OTl);
  // proj-GEMM: A = OT (permuted); out [t][b][c]
  k_gemm_store<<<1024, 256, 0, stream>>>(OTh, OTl, wph, wpl, p_b, out, 4096, 256);
}